// Round 3
// baseline (35.850 us; speedup 1.0000x reference)
//
#include <hip/hip_runtime.h>
#include <math.h>

#define BLK 256
#define INF 3.4e38f

// Kernel 0: pack clouds as float4 {x, y, z, 0.5*(x^2+y^2+z^2)}.
// pack[0 .. BN) = preds, pack[BN .. 2BN) = gts.
__global__ __launch_bounds__(BLK) void sdf_pack(
    const float* __restrict__ gts, const float* __restrict__ preds,
    float4* __restrict__ pack, int BN)
{
    const int i = blockIdx.x * BLK + threadIdx.x;
    if (i < BN) {
        float a = preds[3 * i], b = preds[3 * i + 1], c = preds[3 * i + 2];
        pack[i] = make_float4(a, b, c, 0.5f * (a * a + b * b + c * c));
        a = gts[3 * i]; b = gts[3 * i + 1]; c = gts[3 * i + 2];
        pack[BN + i] = make_float4(a, b, c, 0.5f * (a * a + b * b + c * c));
    }
}

// Kernel 1: per thread (b,s): t_j = hy_j - x.y_j over the chunk's points for
// both clouds (3 FMA + fused min per point), via block-uniform scalar loads.
// Stores u = hx + min_j t_j  (so d = sqrt(max(2u,0)) later).
__global__ __launch_bounds__(BLK) void sdf_partial_min(
    const float* __restrict__ grid,   // [B,S,3]
    const float4* __restrict__ pack,  // [2][B*N]
    float* __restrict__ partial,      // [2][nchunk][B][S]
    int B, int S, int N, int nchunk, int csize)
{
    const int tid   = threadIdx.x;
    const int stile = blockIdx.x;
    const int chunk = blockIdx.y;
    const int b     = blockIdx.z;
    const int s     = stile * BLK + tid;

    const float* xp = grid + ((size_t)b * S + s) * 3;
    const float x0 = -xp[0], x1 = -xp[1], x2 = -xp[2];
    const float hx = 0.5f * (x0 * x0 + x1 * x1 + x2 * x2);

    const float4* pp = pack + (size_t)b * N + (size_t)chunk * csize;
    const float4* gg = pp + (size_t)B * N;

    float tp0 = INF, tp1 = INF, tg0 = INF, tg1 = INF;

    #pragma unroll 2
    for (int j = 0; j < csize; j += 4) {
        float4 p0 = pp[j + 0], p1 = pp[j + 1], p2 = pp[j + 2], p3 = pp[j + 3];
        float ta = fmaf(x0, p0.x, fmaf(x1, p0.y, fmaf(x2, p0.z, p0.w)));
        float tb = fmaf(x0, p1.x, fmaf(x1, p1.y, fmaf(x2, p1.z, p1.w)));
        tp0 = fminf(tp0, fminf(ta, tb));
        float tc = fmaf(x0, p2.x, fmaf(x1, p2.y, fmaf(x2, p2.z, p2.w)));
        float td = fmaf(x0, p3.x, fmaf(x1, p3.y, fmaf(x2, p3.z, p3.w)));
        tp1 = fminf(tp1, fminf(tc, td));

        float4 g0 = gg[j + 0], g1 = gg[j + 1], g2 = gg[j + 2], g3 = gg[j + 3];
        ta = fmaf(x0, g0.x, fmaf(x1, g0.y, fmaf(x2, g0.z, g0.w)));
        tb = fmaf(x0, g1.x, fmaf(x1, g1.y, fmaf(x2, g1.z, g1.w)));
        tg0 = fminf(tg0, fminf(ta, tb));
        tc = fmaf(x0, g2.x, fmaf(x1, g2.y, fmaf(x2, g2.z, g2.w)));
        td = fmaf(x0, g3.x, fmaf(x1, g3.y, fmaf(x2, g3.z, g3.w)));
        tg1 = fminf(tg1, fminf(tc, td));
    }

    const float tp = fminf(tp0, tp1);
    const float tg = fminf(tg0, tg1);

    const size_t sb = (size_t)B * S;
    const size_t base = (size_t)b * S + s;
    partial[(size_t)chunk * sb + base] = hx + tp;
    partial[(size_t)(nchunk + chunk) * sb + base] = hx + tg;
}

// Kernel 2: per (tile,b): min over chunks, d = sqrt(max(2u,0)), |diff|,
// block-sum -> pb[b*ntile + tile].
__global__ __launch_bounds__(BLK) void sdf_reduce(
    const float* __restrict__ partial, float* __restrict__ pb,
    int B, int S, int nchunk)
{
    const int tile = blockIdx.x;
    const int b    = blockIdx.y;
    const int tid  = threadIdx.x;
    const int s    = tile * BLK + tid;

    const size_t sb = (size_t)B * S;
    const size_t base = (size_t)b * S + s;

    float mp = INF, mg = INF;
    #pragma unroll 8
    for (int c = 0; c < nchunk; ++c) {
        mp = fminf(mp, partial[(size_t)c * sb + base]);
        mg = fminf(mg, partial[(size_t)(nchunk + c) * sb + base]);
    }

    float v = fabsf(sqrtf(fmaxf(2.f * mp, 0.f)) - sqrtf(fmaxf(2.f * mg, 0.f)));

    #pragma unroll
    for (int off = 32; off > 0; off >>= 1)
        v += __shfl_down(v, off, 64);

    __shared__ float wsum[BLK / 64];
    if ((tid & 63) == 0) wsum[tid >> 6] = v;
    __syncthreads();
    if (tid == 0) {
        float t = 0.f;
        #pragma unroll
        for (int w = 0; w < BLK / 64; ++w) t += wsum[w];
        pb[b * gridDim.x + tile] = t;
    }
}

// Kernel 3: final tiny reduction.
__global__ __launch_bounds__(64) void sdf_final(
    const float* __restrict__ pb, float* __restrict__ out,
    int B, int S, int ntile)
{
    const int tid = threadIdx.x;
    float v = (tid < B * ntile) ? pb[tid] : 0.f;
    #pragma unroll
    for (int off = 8; off > 0; off >>= 1)
        v += __shfl_down(v, off, 16);
    if (tid < B * ntile && (tid & 15) == 0)
        out[tid / 16] = v / (float)S;
}

extern "C" void kernel_launch(void* const* d_in, const int* in_sizes, int n_in,
                              void* d_out, int out_size, void* d_ws, size_t ws_size,
                              hipStream_t stream) {
    const float* grid  = (const float*)d_in[0];
    const float* gts   = (const float*)d_in[1];
    const float* preds = (const float*)d_in[2];
    float* out = (float*)d_out;

    const int B = 4, S = 4096, N = 4096;
    const int BN = B * N;

    // ws layout: pack (2*BN float4) | partial (2*nchunk*B*S float) | pb (64 f)
    const size_t pack_bytes = (size_t)2 * BN * sizeof(float4);      // 512 KB
    const size_t per_chunk  = (size_t)2 * B * S * sizeof(float);    // 128 KB
    int nchunk = 32;
    while (nchunk > 1 &&
           pack_bytes + (size_t)nchunk * per_chunk + 256 > ws_size) nchunk >>= 1;
    const int csize = N / nchunk;

    float4* pack   = (float4*)d_ws;
    float* partial = (float*)((char*)d_ws + pack_bytes);
    float* pb      = partial + (size_t)2 * nchunk * B * S;

    sdf_pack<<<(BN + BLK - 1) / BLK, BLK, 0, stream>>>(gts, preds, pack, BN);

    dim3 g1(S / BLK, nchunk, B);
    sdf_partial_min<<<g1, BLK, 0, stream>>>(grid, pack, partial,
                                            B, S, N, nchunk, csize);
    const int ntile = S / BLK;   // 16
    dim3 g2(ntile, B);
    sdf_reduce<<<g2, BLK, 0, stream>>>(partial, pb, B, S, nchunk);
    sdf_final<<<1, 64, 0, stream>>>(pb, out, B, S, ntile);
}

// Round 4
// 24.328 us; speedup vs baseline: 1.4736x; 1.4736x over previous
//
#include <hip/hip_runtime.h>
#include <math.h>

#define BLK 256
#define SUBC 128          // cloud points per LDS stage pass
#define SPT 2             // grid points per thread
#define INF 3.4e38f

// Kernel 1: each thread owns SPT grid points; block stages a cloud chunk into
// LDS packed as float4{y0,y1,y2, 0.5*|y|^2}; inner loop = broadcast
// ds_read_b128 + FMA/min3 chains on t_j = hy_j - x.y_j (Gram form).
// Stores u = hx + min_j t_j ; d = sqrt(max(2u,0)) applied in reduce.
__global__ __launch_bounds__(BLK) void sdf_partial_min(
    const float* __restrict__ grid,   // [B,S,3]
    const float* __restrict__ gts,    // [B,N,3]
    const float* __restrict__ preds,  // [B,N,3]
    float* __restrict__ partial,      // [2][nchunk][B][S]
    int B, int S, int N, int nchunk, int csize)
{
    __shared__ float4 rawp4[SUBC * 3 / 4];   // 96 float4 = 384 floats
    __shared__ float4 rawg4[SUBC * 3 / 4];
    __shared__ float4 lp[SUBC];
    __shared__ float4 lg[SUBC];

    const int tid   = threadIdx.x;
    const int stile = blockIdx.x;            // S / (BLK*SPT) tiles
    const int chunk = blockIdx.y;
    const int b     = blockIdx.z;

    const int s0 = stile * (BLK * SPT) + tid;
    const int s1 = s0 + BLK;

    const float* xpA = grid + ((size_t)b * S + s0) * 3;
    const float* xpB = grid + ((size_t)b * S + s1) * 3;
    const float xA0 = -xpA[0], xA1 = -xpA[1], xA2 = -xpA[2];
    const float xB0 = -xpB[0], xB1 = -xpB[1], xB2 = -xpB[2];
    const float hxA = 0.5f * (xA0 * xA0 + xA1 * xA1 + xA2 * xA2);
    const float hxB = 0.5f * (xB0 * xB0 + xB1 * xB1 + xB2 * xB2);

    const int n0 = chunk * csize;
    const float* pbase = preds + ((size_t)b * N + n0) * 3;
    const float* gbase = gts   + ((size_t)b * N + n0) * 3;

    float tpA0 = INF, tpA1 = INF, tgA0 = INF, tgA1 = INF;
    float tpB0 = INF, tpB1 = INF, tgB0 = INF, tgB1 = INF;

    for (int nn = 0; nn < csize; nn += SUBC) {
        __syncthreads();   // protect LDS reuse across stage passes
        // stage raw chunk (16B-aligned: nn*3*4 and base offsets are /16)
        const float4* pv = (const float4*)(pbase + (size_t)nn * 3);
        const float4* gv = (const float4*)(gbase + (size_t)nn * 3);
        if (tid < SUBC * 3 / 4)
            rawp4[tid] = pv[tid];
        else if (tid < SUBC * 3 / 2)
            rawg4[tid - SUBC * 3 / 4] = gv[tid - SUBC * 3 / 4];
        __syncthreads();
        // pack with hy (3-stride LDS reads: 3 coprime 32 -> conflict-free)
        {
            const float* rp = (const float*)rawp4;
            const float* rg = (const float*)rawg4;
            if (tid < SUBC) {
                float a = rp[3 * tid], c1 = rp[3 * tid + 1], c2 = rp[3 * tid + 2];
                lp[tid] = make_float4(a, c1, c2, 0.5f * (a * a + c1 * c1 + c2 * c2));
            } else {
                int j = tid - SUBC;
                float a = rg[3 * j], c1 = rg[3 * j + 1], c2 = rg[3 * j + 2];
                lg[j] = make_float4(a, c1, c2, 0.5f * (a * a + c1 * c1 + c2 * c2));
            }
        }
        __syncthreads();

        #pragma unroll 2
        for (int j = 0; j < SUBC; j += 4) {
            float4 p0 = lp[j], p1 = lp[j + 1], p2 = lp[j + 2], p3 = lp[j + 3];
            float a0 = fmaf(xA0, p0.x, fmaf(xA1, p0.y, fmaf(xA2, p0.z, p0.w)));
            float a1 = fmaf(xA0, p1.x, fmaf(xA1, p1.y, fmaf(xA2, p1.z, p1.w)));
            float a2 = fmaf(xA0, p2.x, fmaf(xA1, p2.y, fmaf(xA2, p2.z, p2.w)));
            float a3 = fmaf(xA0, p3.x, fmaf(xA1, p3.y, fmaf(xA2, p3.z, p3.w)));
            tpA0 = fminf(tpA0, fminf(a0, a1));   // v_min3 shape
            tpA1 = fminf(tpA1, fminf(a2, a3));
            float b0 = fmaf(xB0, p0.x, fmaf(xB1, p0.y, fmaf(xB2, p0.z, p0.w)));
            float b1 = fmaf(xB0, p1.x, fmaf(xB1, p1.y, fmaf(xB2, p1.z, p1.w)));
            float b2 = fmaf(xB0, p2.x, fmaf(xB1, p2.y, fmaf(xB2, p2.z, p2.w)));
            float b3 = fmaf(xB0, p3.x, fmaf(xB1, p3.y, fmaf(xB2, p3.z, p3.w)));
            tpB0 = fminf(tpB0, fminf(b0, b1));
            tpB1 = fminf(tpB1, fminf(b2, b3));

            float4 g0 = lg[j], g1 = lg[j + 1], g2 = lg[j + 2], g3 = lg[j + 3];
            a0 = fmaf(xA0, g0.x, fmaf(xA1, g0.y, fmaf(xA2, g0.z, g0.w)));
            a1 = fmaf(xA0, g1.x, fmaf(xA1, g1.y, fmaf(xA2, g1.z, g1.w)));
            a2 = fmaf(xA0, g2.x, fmaf(xA1, g2.y, fmaf(xA2, g2.z, g2.w)));
            a3 = fmaf(xA0, g3.x, fmaf(xA1, g3.y, fmaf(xA2, g3.z, g3.w)));
            tgA0 = fminf(tgA0, fminf(a0, a1));
            tgA1 = fminf(tgA1, fminf(a2, a3));
            b0 = fmaf(xB0, g0.x, fmaf(xB1, g0.y, fmaf(xB2, g0.z, g0.w)));
            b1 = fmaf(xB0, g1.x, fmaf(xB1, g1.y, fmaf(xB2, g1.z, g1.w)));
            b2 = fmaf(xB0, g2.x, fmaf(xB1, g2.y, fmaf(xB2, g2.z, g2.w)));
            b3 = fmaf(xB0, g3.x, fmaf(xB1, g3.y, fmaf(xB2, g3.z, g3.w)));
            tgB0 = fminf(tgB0, fminf(b0, b1));
            tgB1 = fminf(tgB1, fminf(b2, b3));
        }
    }

    const size_t sb = (size_t)B * S;
    const size_t baseA = (size_t)b * S + s0;
    partial[(size_t)chunk * sb + baseA] = hxA + fminf(tpA0, tpA1);
    partial[(size_t)(nchunk + chunk) * sb + baseA] = hxA + fminf(tgA0, tgA1);
    const size_t baseB = baseA + BLK;
    partial[(size_t)chunk * sb + baseB] = hxB + fminf(tpB0, tpB1);
    partial[(size_t)(nchunk + chunk) * sb + baseB] = hxB + fminf(tgB0, tgB1);
}

// Kernel 2: per (tile,b): min over chunks, d = sqrt(max(2u,0)), |diff|,
// block-sum -> pb[b*ntile + tile].
__global__ __launch_bounds__(BLK) void sdf_reduce(
    const float* __restrict__ partial, float* __restrict__ pb,
    int B, int S, int nchunk)
{
    const int tile = blockIdx.x;
    const int b    = blockIdx.y;
    const int tid  = threadIdx.x;
    const int s    = tile * BLK + tid;

    const size_t sb = (size_t)B * S;
    const size_t base = (size_t)b * S + s;

    float mp = INF, mg = INF;
    #pragma unroll 8
    for (int c = 0; c < nchunk; ++c) {
        mp = fminf(mp, partial[(size_t)c * sb + base]);
        mg = fminf(mg, partial[(size_t)(nchunk + c) * sb + base]);
    }

    float v = fabsf(sqrtf(fmaxf(2.f * mp, 0.f)) - sqrtf(fmaxf(2.f * mg, 0.f)));

    #pragma unroll
    for (int off = 32; off > 0; off >>= 1)
        v += __shfl_down(v, off, 64);

    __shared__ float wsum[BLK / 64];
    if ((tid & 63) == 0) wsum[tid >> 6] = v;
    __syncthreads();
    if (tid == 0) {
        float t = 0.f;
        #pragma unroll
        for (int w = 0; w < BLK / 64; ++w) t += wsum[w];
        pb[b * gridDim.x + tile] = t;
    }
}

// Kernel 3: final tiny reduction.
__global__ __launch_bounds__(64) void sdf_final(
    const float* __restrict__ pb, float* __restrict__ out,
    int B, int S, int ntile)
{
    const int tid = threadIdx.x;
    float v = (tid < B * ntile) ? pb[tid] : 0.f;
    #pragma unroll
    for (int off = 8; off > 0; off >>= 1)
        v += __shfl_down(v, off, 16);
    if (tid < B * ntile && (tid & 15) == 0)
        out[tid / 16] = v / (float)S;
}

extern "C" void kernel_launch(void* const* d_in, const int* in_sizes, int n_in,
                              void* d_out, int out_size, void* d_ws, size_t ws_size,
                              hipStream_t stream) {
    const float* grid  = (const float*)d_in[0];
    const float* gts   = (const float*)d_in[1];
    const float* preds = (const float*)d_in[2];
    float* out = (float*)d_out;
    float* ws  = (float*)d_ws;

    const int B = 4, S = 4096, N = 4096;

    // partial needs 2*nchunk*B*S floats + 64 floats for pb
    const size_t per_chunk = (size_t)2 * B * S * sizeof(float);  // 128 KB
    int nchunk = 32;
    while (nchunk > 1 &&
           (size_t)nchunk * per_chunk + 256 > ws_size) nchunk >>= 1;
    const int csize = N / nchunk;    // 128 at nchunk=32 (multiple of SUBC)

    float* partial = ws;
    float* pb      = partial + (size_t)2 * nchunk * B * S;

    dim3 g1(S / (BLK * SPT), nchunk, B);   // (8, 32, 4) = 1024 blocks
    sdf_partial_min<<<g1, BLK, 0, stream>>>(grid, gts, preds, partial,
                                            B, S, N, nchunk, csize);
    const int ntile = S / BLK;             // 16
    dim3 g2(ntile, B);
    sdf_reduce<<<g2, BLK, 0, stream>>>(partial, pb, B, S, nchunk);
    sdf_final<<<1, 64, 0, stream>>>(pb, out, B, S, ntile);
}